// Round 17
// baseline (260.075 us; speedup 1.0000x reference)
//
#include <hip/hip_runtime.h>
#include <hip/hip_bf16.h>
#include <cstdint>
#include <cstddef>

// ---------------- wave helpers (wave64) ----------------
__device__ __forceinline__ float wave_max_f(float v){
  #pragma unroll
  for (int m = 32; m; m >>= 1) v = fmaxf(v, __shfl_xor(v, m));
  return v;
}
__device__ __forceinline__ float wave_sum_f(float v){
  #pragma unroll
  for (int m = 32; m; m >>= 1) v += __shfl_xor(v, m);
  return v;
}
__device__ __forceinline__ int wave_sum_i(int v){
  #pragma unroll
  for (int m = 32; m; m >>= 1) v += __shfl_xor(v, m);
  return v;
}

// ---------------- qs_attn constants ----------------
#define C3   256
#define HW3  4096
#define NP   64

// ---------------- _sample_early body (one wave per output row) ------------
template<int C, int LOGHW>
__device__ __forceinline__ void sample_body(const float* __restrict__ feat,
                                            const int* __restrict__ pid,
                                            float* __restrict__ out,
                                            int r, int lane){
  const int b = r >> 6, p = r & 63;
  const int l = pid[p];
  const float* fb = feat + (((size_t)b * C) << LOGHW);
  constexpr int V = C / 64;
  float v[V];
  float sq = 0.f;
  #pragma unroll
  for (int i = 0; i < V; ++i){
    const int c = lane + 64 * i;
    v[i] = fb[(((size_t)c) << LOGHW) + l];
    sq += v[i] * v[i];
  }
  sq = wave_sum_f(sq);
  const float nrm = fmaxf(sqrtf(sq), 1e-7f);
  #pragma unroll
  for (int i = 0; i < V; ++i)
    out[(size_t)r * C + lane + 64 * i] = v[i] / nrm;
}

// ---------------- local dots: 16-wave blocks, fr staged in LDS ------------
__global__ __launch_bounds__(1024, 8)
void ldots_kernel(const float* __restrict__ feat3, float* __restrict__ dotsl,
                  const float* __restrict__ f0, const float* __restrict__ f1,
                  const float* __restrict__ f2,
                  const int* __restrict__ p0, const int* __restrict__ p1,
                  const int* __restrict__ p2,
                  float* __restrict__ o0, float* __restrict__ o1,
                  float* __restrict__ o2){
  __shared__ float fr_sh[C3 * 64];   // 64 KB: fr_sh[c2*64 + w]
  const int raw = blockIdx.x;
  const int tid = threadIdx.x, wid = tid >> 6, lane = tid & 63;

  if (raw >= 512){                      // ---- fused _sample_early tail
    const int sidx = ((raw - 512) << 4) | wid;    // 0..383
    const int g = sidx >> 7, r = sidx & 127;
    if (g == 0)      sample_body<64, 16>(f0, p0, o0, r, lane);
    else if (g == 1) sample_body<128, 14>(f1, p1, o1, r, lane);
    else             sample_body<256, 12>(f2, p2, o2, r, lane);
    return;
  }

  const int work = (raw & 7) * 64 + (raw >> 3);   // bijective: 512 = 8*64
  const int kg = work & 3;
  const int bh = work >> 2;
  const int b = bh >> 6, h = bh & 63;
  const int w = lane;
  const float* fb = feat3 + ((size_t)b << 20);

  { // cooperative fr stage: wave wid loads c2 in [wid*16, wid*16+16)
    const int c2b = wid << 4;
    #pragma unroll
    for (int j = 0; j < 16; ++j){
      const int c2 = c2b + j;
      fr_sh[(c2 << 6) + w] = fb[((size_t)c2 << 12) + (h << 6) + w];
    }
  }
  __syncthreads();

  const int k2v = (wid << 2) | kg;      // balanced 13/12/12/12 split
  if (k2v >= 49) return;                // after barrier: safe
  const int k2 = __builtin_amdgcn_readfirstlane(k2v);
  const float* fr_w = fr_sh + w;        // fr value: fr_w[c2 << 6]
  const int f0i = k2 << 8;
  const int c0 = f0i / 49;
  const int k0 = f0i - c0 * 49;

  int   vof[7];
  float msk[7];
  #pragma unroll
  for (int kj = 0; kj < 7; ++kj){
    const int s = w + kj - 3;
    msk[kj] = ((unsigned)s < 64u) ? 1.f : 0.f;
    vof[kj] = s < 0 ? 0 : (s > 63 ? 63 : s);
  }

  float acc = 0.f;
  int c2 = 0;

  auto partial = [&](int c, int klo, int khi){
    for (int k = klo; k < khi; ++k){
      const int ki = k / 7, kj = k - (k / 7) * 7;
      const int hh = h + ki - 3;
      float wv = 0.f;
      if ((unsigned)hh < 64u){
        const int sw = w + kj - 3;
        const int swc = sw < 0 ? 0 : (sw > 63 ? 63 : sw);
        const float x = fb[((size_t)c << 12) + (hh << 6) + swc];
        wv = ((unsigned)sw < 64u) ? x : 0.f;
      }
      acc = fmaf(wv, fr_w[c2 << 6], acc);
      ++c2;
    }
  };

  partial(c0, k0, 49);

  #pragma unroll
  for (int j = 1; j <= 4; ++j){
    const int c = c0 + j;
    const float* chan = fb + ((size_t)c << 12);
    #pragma unroll
    for (int ki = 0; ki < 7; ++ki){
      const int hh = h + ki - 3;
      if ((unsigned)hh < 64u){                 // wave-uniform scalar branch
        const float* row = chan + (hh << 6);
        #pragma unroll
        for (int kj = 0; kj < 7; ++kj){
          const float x = row[vof[kj]];
          acc = fmaf(x * msk[kj], fr_w[(c2 + ki * 7 + kj) << 6], acc);
        }
      }
    }
    c2 += 49;
  }

  {
    const int rem = 11 + k0;
    const int khi = rem < 49 ? rem : 49;
    partial(c0 + 5, 0, khi);
    if (rem > 49) partial(c0 + 6, 0, rem - 49);
  }

  dotsl[(((size_t)(b * 49 + k2)) << 12) + (h << 6) + w] = acc;
}

// ---------------- local entropy (softmax over 49, k-major layout) ----------
__global__ __launch_bounds__(64)
void lent_kernel(const float* __restrict__ dotsl, float* __restrict__ ent){
  const int blk = blockIdx.x;       // 128
  const int b = blk >> 6;
  const int l = ((blk & 63) << 6) + threadIdx.x;
  const float* dl = dotsl + (((size_t)b * 49) << 12);
  float m = -INFINITY;
  #pragma unroll
  for (int k = 0; k < 49; ++k) m = fmaxf(m, dl[((size_t)k << 12) + l]);
  float s = 0.f, ts = 0.f;
  #pragma unroll
  for (int k = 0; k < 49; ++k){
    const float d = dl[((size_t)k << 12) + l] - m;
    const float e = expf(d);
    s += e; ts += e * d;
  }
  ent[b * HW3 + l] = logf(s) - ts / s;
}

// ---------------- rank-based top-64 selection (stable, exact) -------------
__global__ __launch_bounds__(256)
void rank_select_kernel(const float* __restrict__ ent, int* __restrict__ idx){
  __shared__ unsigned long long keys[HW3];   // 32 KB
  const int blk = blockIdx.x;
  const int b  = blk >> 6;
  const int cg = blk & 63;                   // 64 candidates per block
  const int t = threadIdx.x, wid = t >> 6, lane = t & 63;
  for (int i = t; i < HW3; i += 256){
    const float e = ent[b * HW3 + i];
    unsigned u = __float_as_uint(e);
    u = (u & 0x80000000u) ? ~u : (u | 0x80000000u);
    keys[i] = ((unsigned long long)u << 32) | (unsigned)i;
  }
  __syncthreads();
  #pragma unroll
  for (int j = 0; j < 16; ++j){
    const int cand = (cg << 6) + (wid << 4) + j;
    const unsigned long long kc = keys[cand];
    int cnt = 0;
    #pragma unroll 8
    for (int i = lane; i < HW3; i += 64)
      cnt += (keys[i] < kc) ? 1 : 0;
    cnt = wave_sum_i(cnt);
    if (lane == 0 && cnt < NP) idx[b * NP + cnt] = cand;
  }
}

// ---------------- global dots: 4 query rows per block ---------------------
__global__ __launch_bounds__(256)
void gdots_kernel(const float* __restrict__ feat3, const int* __restrict__ idx,
                  float* __restrict__ dg, float* __restrict__ bmax){
  __shared__ float4 q_int[C3];     // q_int[c] = {q0,q1,q2,q3}[c]
  __shared__ float red4[4][4];     // [wid][q]
  const int raw = blockIdx.x;
  const int work = (raw & 7) * 64 + (raw >> 3);   // 512 = 8*64
  const int bpg = work >> 4, lc = work & 15;      // bpg in 0..31
  const int b = bpg >> 4;
  const int bp0 = (b << 6) + ((bpg & 15) << 2);
  const int t = threadIdx.x, lane = t & 63, wid = t >> 6;
  const float* fb = feat3 + ((size_t)b << 20);
  {
    float4 qv;
    qv.x = fb[((size_t)t << 12) + idx[bp0 + 0]];
    qv.y = fb[((size_t)t << 12) + idx[bp0 + 1]];
    qv.z = fb[((size_t)t << 12) + idx[bp0 + 2]];
    qv.w = fb[((size_t)t << 12) + idx[bp0 + 3]];
    q_int[t] = qv;
  }
  __syncthreads();
  const int l = (lc << 8) + t;
  float a0 = 0.f, a1 = 0.f, a2 = 0.f, a3 = 0.f;
  #pragma unroll 8
  for (int c = 0; c < C3; ++c){
    const float fv = fb[((size_t)c << 12) + l];
    const float4 q = q_int[c];
    a0 = fmaf(fv, q.x, a0); a1 = fmaf(fv, q.y, a1);
    a2 = fmaf(fv, q.z, a2); a3 = fmaf(fv, q.w, a3);
  }
  dg[((size_t)(bp0 + 0) << 12) + l] = a0;
  dg[((size_t)(bp0 + 1) << 12) + l] = a1;
  dg[((size_t)(bp0 + 2) << 12) + l] = a2;
  dg[((size_t)(bp0 + 3) << 12) + l] = a3;
  const float m0 = wave_max_f(a0), m1 = wave_max_f(a1);
  const float m2 = wave_max_f(a2), m3 = wave_max_f(a3);
  if (lane == 0){
    red4[wid][0] = m0; red4[wid][1] = m1;
    red4[wid][2] = m2; red4[wid][3] = m3;
  }
  __syncthreads();
  if (t < 4){
    const float m = fmaxf(fmaxf(red4[0][t], red4[1][t]),
                          fmaxf(red4[2][t], red4[3][t]));
    bmax[(bp0 + t) * 16 + lc] = m;
  }
}

// ---------------- softmax fill: dg -> p in place (R13's, measured cheap) --
__global__ __launch_bounds__(256)
void pfill_kernel(float* __restrict__ dg, const float* __restrict__ bmax){
  __shared__ float red[4];
  const int bp = blockIdx.x, t = threadIdx.x, lane = t & 63, wid = t >> 6;
  float m = -INFINITY;
  #pragma unroll
  for (int i = 0; i < 16; ++i) m = fmaxf(m, bmax[bp * 16 + i]);
  float e[16];
  float s = 0.f;
  #pragma unroll
  for (int i = 0; i < 16; ++i){
    e[i] = expf(dg[((size_t)bp << 12) + (i << 8) + t] - m);
    s += e[i];
  }
  s = wave_sum_f(s);
  if (lane == 0) red[wid] = s;
  __syncthreads();
  const float inv = 1.f / (red[0] + red[1] + red[2] + red[3]);
  #pragma unroll
  for (int i = 0; i < 16; ++i)
    dg[((size_t)bp << 12) + (i << 8) + t] = e[i] * inv;
}

// ---------------- PV: 16-wave monolith, p staged in LDS -------------------
// Same grid/XCD map/traffic as the 44-us round-10 shape (grid 256; block =
// 4 q-rows x 32 ch x full l), but 1024 threads (16 waves = 4 waves/SIMD,
// 4x latency hiding) and NO stats phase (pfill did softmax): stage = direct
// float4 copy of the 4 p rows into LDS pp[q][l4]; wave owns 2 channels
// (acc[2][4], live-set ~45 VGPR << 128 cap at 16 waves). Compute values and
// order identical to round-16 (a.x*p_l0 + a.y*p_l1 + ...) -> absmax 0.0.
__global__ __launch_bounds__(1024)
void pv_kernel(const float* __restrict__ feat3, const float* __restrict__ p,
               float* __restrict__ outraw){
  __shared__ float4 pp[4 * 1024];  // 64 KB: pp[q*1024 + l4] = p_rowq[4l4..+3]
  const int raw = blockIdx.x;
  const int work = (raw & 7) * 32 + (raw >> 3);   // bijective: 256 = 8*32
  const int cg = work >> 5;        // == raw & 7 (XCD-pinned channel group)
  const int rest = work & 31;      // b*16 + pg
  const int b = rest >> 4, pg = rest & 15;
  const int bp0 = (b << 6) + (pg << 2);
  const int t = threadIdx.x, lane = t & 63, wid = t >> 6;
  const float* fb = feat3 + ((size_t)b << 20);

  // stage: direct float4 copy, coalesced global read + contiguous LDS write
  #pragma unroll
  for (int q = 0; q < 4; ++q){
    const float4* rowq = reinterpret_cast<const float4*>(
        p + ((size_t)(bp0 + q) << 12));
    pp[(q << 10) + t] = rowq[t];
  }
  __syncthreads();

  // compute: wave owns 2 channels
  const int c0 = (cg << 5) + (wid << 1);
  float acc[2][4];
  #pragma unroll
  for (int j = 0; j < 2; ++j)
    #pragma unroll
    for (int q = 0; q < 4; ++q) acc[j][q] = 0.f;

  for (int ii = 0; ii < 16; ++ii){
    const int l4 = (ii << 6) + lane;
    const float4 q0 = pp[l4];
    const float4 q1 = pp[1024 + l4];
    const float4 q2 = pp[2048 + l4];
    const float4 q3 = pp[3072 + l4];
    #pragma unroll
    for (int j = 0; j < 2; ++j){
      const float4 a = *reinterpret_cast<const float4*>(
          fb + (((size_t)(c0 + j)) << 12) + 4 * (size_t)l4);
      acc[j][0] += a.x * q0.x + a.y * q0.y + a.z * q0.z + a.w * q0.w;
      acc[j][1] += a.x * q1.x + a.y * q1.y + a.z * q1.z + a.w * q1.w;
      acc[j][2] += a.x * q2.x + a.y * q2.y + a.z * q2.z + a.w * q2.w;
      acc[j][3] += a.x * q3.x + a.y * q3.y + a.z * q3.z + a.w * q3.w;
    }
  }
  #pragma unroll
  for (int j = 0; j < 2; ++j){
    #pragma unroll
    for (int q = 0; q < 4; ++q){
      const float v = wave_sum_f(acc[j][q]);
      if (lane == 0) outraw[(bp0 + q) * C3 + c0 + j] = v;
    }
  }
}

// ---------------- normalize rows of 256 ----------------
__global__ __launch_bounds__(256)
void norm_kernel(const float* __restrict__ outraw, float* __restrict__ out3){
  __shared__ float red[4];
  const int bp = blockIdx.x, t = threadIdx.x, lane = t & 63, wid = t >> 6;
  const float v = outraw[bp * C3 + t];
  const float sq = wave_sum_f(v * v);
  if (lane == 0) red[wid] = sq;
  __syncthreads();
  const float nrm = fmaxf(sqrtf(red[0] + red[1] + red[2] + red[3]), 1e-7f);
  out3[(size_t)bp * C3 + t] = v / nrm;
}

// ---------------- launch ----------------
extern "C" void kernel_launch(void* const* d_in, const int* in_sizes, int n_in,
                              void* d_out, int out_size, void* d_ws, size_t ws_size,
                              hipStream_t stream){
  const float* feat0 = (const float*)d_in[0];
  const float* feat1 = (const float*)d_in[1];
  const float* feat2 = (const float*)d_in[2];
  const float* feat3 = (const float*)d_in[3];
  const int*   pid0  = (const int*)d_in[4];
  const int*   pid1  = (const int*)d_in[5];
  const int*   pid2  = (const int*)d_in[6];

  float* out  = (float*)d_out;
  float* out0 = out;                 // 128*64
  float* out1 = out + 8192;          // 128*128
  float* out2 = out + 24576;         // 128*256
  float* out3 = out + 57344;         // 128*256

  float* ws       = (float*)d_ws;
  float* ent_ws   = ws;                         // 8192
  int*   idx_ws   = (int*)(ws + 8192);          // 128
  float* dotsl_ws = ws + 8320;                  // 2*49*4096 = 401408
  float* dg_ws    = dotsl_ws + 401408;          // 128*4096  = 524288 (-> p in place)
  float* bmax_ws  = dg_ws + 524288;             // 128*16
  float* oraw_ws  = bmax_ws + 2048;             // 128*256

  ldots_kernel<<<536, 1024, 0, stream>>>(feat3, dotsl_ws,
                                         feat0, feat1, feat2,
                                         pid0, pid1, pid2,
                                         out0, out1, out2);
  lent_kernel<<<128, 64, 0, stream>>>(dotsl_ws, ent_ws);
  rank_select_kernel<<<128, 256, 0, stream>>>(ent_ws, idx_ws);
  gdots_kernel<<<512, 256, 0, stream>>>(feat3, idx_ws, dg_ws, bmax_ws);
  pfill_kernel<<<128, 256, 0, stream>>>(dg_ws, bmax_ws);
  pv_kernel<<<256, 1024, 0, stream>>>(feat3, dg_ws, oraw_ws);
  norm_kernel<<<128, 256, 0, stream>>>(oraw_ws, out3);
}

// Round 18
// 98.273 us; speedup vs baseline: 2.6465x; 2.6465x over previous
//
#include <hip/hip_runtime.h>
#include <hip/hip_bf16.h>
#include <cstdint>
#include <cstddef>

// ---------------- wave helpers (wave64) ----------------
__device__ __forceinline__ float wave_max_f(float v){
  #pragma unroll
  for (int m = 32; m; m >>= 1) v = fmaxf(v, __shfl_xor(v, m));
  return v;
}
__device__ __forceinline__ float wave_sum_f(float v){
  #pragma unroll
  for (int m = 32; m; m >>= 1) v += __shfl_xor(v, m);
  return v;
}
__device__ __forceinline__ int wave_sum_i(int v){
  #pragma unroll
  for (int m = 32; m; m >>= 1) v += __shfl_xor(v, m);
  return v;
}

// ---------------- qs_attn constants ----------------
#define C3   256
#define HW3  4096
#define NP   64

// ---------------- _sample_early body (one wave per output row) ------------
template<int C, int LOGHW>
__device__ __forceinline__ void sample_body(const float* __restrict__ feat,
                                            const int* __restrict__ pid,
                                            float* __restrict__ out,
                                            int r, int lane){
  const int b = r >> 6, p = r & 63;
  const int l = pid[p];
  const float* fb = feat + (((size_t)b * C) << LOGHW);
  constexpr int V = C / 64;
  float v[V];
  float sq = 0.f;
  #pragma unroll
  for (int i = 0; i < V; ++i){
    const int c = lane + 64 * i;
    v[i] = fb[(((size_t)c) << LOGHW) + l];
    sq += v[i] * v[i];
  }
  sq = wave_sum_f(sq);
  const float nrm = fmaxf(sqrtf(sq), 1e-7f);
  #pragma unroll
  for (int i = 0; i < V; ++i)
    out[(size_t)r * C + lane + 64 * i] = v[i] / nrm;
}

// ---------------- local dots: 16-wave blocks, fr staged in LDS ------------
// blocks 0..511: XCD-swizzled; work=(raw&7)*64+raw>>3; kg=work&3, bh=work>>2.
// All 16 waves cooperatively stage fr (256x64 fl = 64KB) for (b,h); wave wid
// computes k2 = wid*4+kg (13/12/12/12 balanced; k2>=49 exits post-barrier).
// 2 blocks/CU (128KB LDS) x 16 waves = 32 waves/CU. Window loads keep the
// round-6 batchable row-group body; fr reads are conflict-free ds_read.
// Accumulation ascending f -> bit-identical.
// blocks 512..535: fused _sample_early tail (16 rows per block).
__global__ __launch_bounds__(1024, 8)
void ldots_kernel(const float* __restrict__ feat3, float* __restrict__ dotsl,
                  const float* __restrict__ f0, const float* __restrict__ f1,
                  const float* __restrict__ f2,
                  const int* __restrict__ p0, const int* __restrict__ p1,
                  const int* __restrict__ p2,
                  float* __restrict__ o0, float* __restrict__ o1,
                  float* __restrict__ o2){
  __shared__ float fr_sh[C3 * 64];   // 64 KB: fr_sh[c2*64 + w]
  const int raw = blockIdx.x;
  const int tid = threadIdx.x, wid = tid >> 6, lane = tid & 63;

  if (raw >= 512){                      // ---- fused _sample_early tail
    const int sidx = ((raw - 512) << 4) | wid;    // 0..383
    const int g = sidx >> 7, r = sidx & 127;
    if (g == 0)      sample_body<64, 16>(f0, p0, o0, r, lane);
    else if (g == 1) sample_body<128, 14>(f1, p1, o1, r, lane);
    else             sample_body<256, 12>(f2, p2, o2, r, lane);
    return;
  }

  const int work = (raw & 7) * 64 + (raw >> 3);   // bijective: 512 = 8*64
  const int kg = work & 3;
  const int bh = work >> 2;
  const int b = bh >> 6, h = bh & 63;
  const int w = lane;
  const float* fb = feat3 + ((size_t)b << 20);

  { // cooperative fr stage: wave wid loads c2 in [wid*16, wid*16+16)
    const int c2b = wid << 4;
    #pragma unroll
    for (int j = 0; j < 16; ++j){
      const int c2 = c2b + j;
      fr_sh[(c2 << 6) + w] = fb[((size_t)c2 << 12) + (h << 6) + w];
    }
  }
  __syncthreads();

  const int k2v = (wid << 2) | kg;      // balanced 13/12/12/12 split
  if (k2v >= 49) return;                // after barrier: safe
  const int k2 = __builtin_amdgcn_readfirstlane(k2v);
  const float* fr_w = fr_sh + w;        // fr value: fr_w[c2 << 6]
  const int f0i = k2 << 8;
  const int c0 = f0i / 49;
  const int k0 = f0i - c0 * 49;

  int   vof[7];
  float msk[7];
  #pragma unroll
  for (int kj = 0; kj < 7; ++kj){
    const int s = w + kj - 3;
    msk[kj] = ((unsigned)s < 64u) ? 1.f : 0.f;
    vof[kj] = s < 0 ? 0 : (s > 63 ? 63 : s);
  }

  float acc = 0.f;
  int c2 = 0;

  // generic (dynamic-k) step used for head/tail partial channels
  auto partial = [&](int c, int klo, int khi){
    for (int k = klo; k < khi; ++k){
      const int ki = k / 7, kj = k - (k / 7) * 7;
      const int hh = h + ki - 3;
      float wv = 0.f;
      if ((unsigned)hh < 64u){
        const int sw = w + kj - 3;
        const int swc = sw < 0 ? 0 : (sw > 63 ? 63 : sw);
        const float x = fb[((size_t)c << 12) + (hh << 6) + swc];
        wv = ((unsigned)sw < 64u) ? x : 0.f;
      }
      acc = fmaf(wv, fr_w[c2 << 6], acc);
      ++c2;
    }
  };

  partial(c0, k0, 49);

  #pragma unroll
  for (int j = 1; j <= 4; ++j){
    const int c = c0 + j;
    const float* chan = fb + ((size_t)c << 12);
    #pragma unroll
    for (int ki = 0; ki < 7; ++ki){
      const int hh = h + ki - 3;
      if ((unsigned)hh < 64u){                 // wave-uniform scalar branch
        const float* row = chan + (hh << 6);
        #pragma unroll
        for (int kj = 0; kj < 7; ++kj){
          const float x = row[vof[kj]];
          acc = fmaf(x * msk[kj], fr_w[(c2 + ki * 7 + kj) << 6], acc);
        }
      }
    }
    c2 += 49;
  }

  {
    const int rem = 11 + k0;
    const int khi = rem < 49 ? rem : 49;
    partial(c0 + 5, 0, khi);
    if (rem > 49) partial(c0 + 6, 0, rem - 49);
  }

  dotsl[(((size_t)(b * 49 + k2)) << 12) + (h << 6) + w] = acc;
}

// ---------------- local entropy (softmax over 49, k-major layout) ----------
// grid 128 x 64: one wave per 64 positions, spread over 128 CUs.
__global__ __launch_bounds__(64)
void lent_kernel(const float* __restrict__ dotsl, float* __restrict__ ent){
  const int blk = blockIdx.x;       // 128
  const int b = blk >> 6;
  const int l = ((blk & 63) << 6) + threadIdx.x;
  const float* dl = dotsl + (((size_t)b * 49) << 12);
  float m = -INFINITY;
  #pragma unroll
  for (int k = 0; k < 49; ++k) m = fmaxf(m, dl[((size_t)k << 12) + l]);
  float s = 0.f, ts = 0.f;
  #pragma unroll
  for (int k = 0; k < 49; ++k){
    const float d = dl[((size_t)k << 12) + l] - m;
    const float e = expf(d);
    s += e; ts += e * d;
  }
  ent[b * HW3 + l] = logf(s) - ts / s;
}

// ---------------- rank-based top-64 selection (stable, exact) -------------
__global__ __launch_bounds__(256)
void rank_select_kernel(const float* __restrict__ ent, int* __restrict__ idx){
  __shared__ unsigned long long keys[HW3];   // 32 KB
  const int blk = blockIdx.x;
  const int b  = blk >> 6;
  const int cg = blk & 63;                   // 64 candidates per block
  const int t = threadIdx.x, wid = t >> 6, lane = t & 63;
  for (int i = t; i < HW3; i += 256){
    const float e = ent[b * HW3 + i];
    unsigned u = __float_as_uint(e);
    u = (u & 0x80000000u) ? ~u : (u | 0x80000000u);
    keys[i] = ((unsigned long long)u << 32) | (unsigned)i;
  }
  __syncthreads();
  #pragma unroll
  for (int j = 0; j < 16; ++j){
    const int cand = (cg << 6) + (wid << 4) + j;
    const unsigned long long kc = keys[cand];
    int cnt = 0;
    #pragma unroll 8
    for (int i = lane; i < HW3; i += 64)
      cnt += (keys[i] < kc) ? 1 : 0;
    cnt = wave_sum_i(cnt);
    if (lane == 0 && cnt < NP) idx[b * NP + cnt] = cand;
  }
}

// ---------------- global dots: 4 query rows per block ---------------------
__global__ __launch_bounds__(256)
void gdots_kernel(const float* __restrict__ feat3, const int* __restrict__ idx,
                  float* __restrict__ dg, float* __restrict__ bmax){
  __shared__ float4 q_int[C3];     // q_int[c] = {q0,q1,q2,q3}[c]
  __shared__ float red4[4][4];     // [wid][q]
  const int raw = blockIdx.x;
  const int work = (raw & 7) * 64 + (raw >> 3);   // 512 = 8*64
  const int bpg = work >> 4, lc = work & 15;      // bpg in 0..31
  const int b = bpg >> 4;
  const int bp0 = (b << 6) + ((bpg & 15) << 2);
  const int t = threadIdx.x, lane = t & 63, wid = t >> 6;
  const float* fb = feat3 + ((size_t)b << 20);
  {
    float4 qv;
    qv.x = fb[((size_t)t << 12) + idx[bp0 + 0]];
    qv.y = fb[((size_t)t << 12) + idx[bp0 + 1]];
    qv.z = fb[((size_t)t << 12) + idx[bp0 + 2]];
    qv.w = fb[((size_t)t << 12) + idx[bp0 + 3]];
    q_int[t] = qv;
  }
  __syncthreads();
  const int l = (lc << 8) + t;
  float a0 = 0.f, a1 = 0.f, a2 = 0.f, a3 = 0.f;
  #pragma unroll 8
  for (int c = 0; c < C3; ++c){
    const float fv = fb[((size_t)c << 12) + l];
    const float4 q = q_int[c];
    a0 = fmaf(fv, q.x, a0); a1 = fmaf(fv, q.y, a1);
    a2 = fmaf(fv, q.z, a2); a3 = fmaf(fv, q.w, a3);
  }
  dg[((size_t)(bp0 + 0) << 12) + l] = a0;
  dg[((size_t)(bp0 + 1) << 12) + l] = a1;
  dg[((size_t)(bp0 + 2) << 12) + l] = a2;
  dg[((size_t)(bp0 + 3) << 12) + l] = a3;
  const float m0 = wave_max_f(a0), m1 = wave_max_f(a1);
  const float m2 = wave_max_f(a2), m3 = wave_max_f(a3);
  if (lane == 0){
    red4[wid][0] = m0; red4[wid][1] = m1;
    red4[wid][2] = m2; red4[wid][3] = m3;
  }
  __syncthreads();
  if (t < 4){
    const float m = fmaxf(fmaxf(red4[0][t], red4[1][t]),
                          fmaxf(red4[2][t], red4[3][t]));
    bmax[(bp0 + t) * 16 + lc] = m;
  }
}

// ---------------- PV (softmax stats fused, exp kept in regs) --------------
#define PSW(l) ((l) ^ (((l) >> 3) & 7))
__global__ __launch_bounds__(256)
void pv_kernel(const float* __restrict__ feat3, const float* __restrict__ dg,
               const float* __restrict__ bmax, float* __restrict__ outraw){
  __shared__ float4 p_int[HW3];    // 64 KB; floats [0..3] reused as scratch
  float* red = reinterpret_cast<float*>(p_int);
  const int raw = blockIdx.x;
  const int work = (raw & 7) * 32 + (raw >> 3);   // 256 = 8*32
  const int bpg = work >> 3, cg = work & 7;
  const int b = bpg >> 4;
  const int bp0 = (b << 6) + ((bpg & 15) << 2);
  const int t = threadIdx.x, lane = t & 63, wid = t >> 6;
  const float* fb = feat3 + ((size_t)b << 20);

  // per-row softmax stats; exp values kept in registers for the p fill
  float e_reg[4][16];
  float iq[4];
  #pragma unroll
  for (int q = 0; q < 4; ++q){
    const int bp = bp0 + q;
    float m = -INFINITY;
    #pragma unroll
    for (int i = 0; i < 16; ++i) m = fmaxf(m, bmax[bp * 16 + i]);
    float s = 0.f;
    #pragma unroll
    for (int i = 0; i < 16; ++i){
      const float e = expf(dg[((size_t)bp << 12) + (i << 8) + t] - m);
      e_reg[q][i] = e;
      s += e;
    }
    s = wave_sum_f(s);
    if (lane == 0) red[wid] = s;
    __syncthreads();
    const float stot = red[0] + red[1] + red[2] + red[3];
    __syncthreads();             // red reused next q / p_int overwritten later
    iq[q] = 1.f / stot;
  }

  #pragma unroll
  for (int i = 0; i < 16; ++i){
    const int l = (i << 8) + t;
    float4 pv;
    pv.x = e_reg[0][i] * iq[0];
    pv.y = e_reg[1][i] * iq[1];
    pv.z = e_reg[2][i] * iq[2];
    pv.w = e_reg[3][i] * iq[3];
    p_int[PSW(l)] = pv;
  }
  __syncthreads();
  float s[8][4];
  #pragma unroll
  for (int j = 0; j < 8; ++j)
    #pragma unroll
    for (int q = 0; q < 4; ++q) s[j][q] = 0.f;

  const int cbase = (cg << 5) + (wid << 3);
  for (int i = 0; i < 16; ++i){
    const int l4 = (i << 6) + lane;          // float4-chunk index over l
    const float4 p0 = p_int[PSW(4 * l4 + 0)];
    const float4 p1 = p_int[PSW(4 * l4 + 1)];
    const float4 p2 = p_int[PSW(4 * l4 + 2)];
    const float4 p3 = p_int[PSW(4 * l4 + 3)];
    #pragma unroll
    for (int j = 0; j < 8; ++j){
      const float4 a = *reinterpret_cast<const float4*>(
          fb + (((size_t)(cbase + j)) << 12) + 4 * (size_t)l4);
      s[j][0] += a.x * p0.x + a.y * p1.x + a.z * p2.x + a.w * p3.x;
      s[j][1] += a.x * p0.y + a.y * p1.y + a.z * p2.y + a.w * p3.y;
      s[j][2] += a.x * p0.z + a.y * p1.z + a.z * p2.z + a.w * p3.z;
      s[j][3] += a.x * p0.w + a.y * p1.w + a.z * p2.w + a.w * p3.w;
    }
  }
  #pragma unroll
  for (int j = 0; j < 8; ++j){
    #pragma unroll
    for (int q = 0; q < 4; ++q){
      const float v = wave_sum_f(s[j][q]);
      if (lane == 0) outraw[(bp0 + q) * C3 + cbase + j] = v;
    }
  }
}

// ---------------- normalize rows of 256 ----------------
__global__ __launch_bounds__(256)
void norm_kernel(const float* __restrict__ outraw, float* __restrict__ out3){
  __shared__ float red[4];
  const int bp = blockIdx.x, t = threadIdx.x, lane = t & 63, wid = t >> 6;
  const float v = outraw[bp * C3 + t];
  const float sq = wave_sum_f(v * v);
  if (lane == 0) red[wid] = sq;
  __syncthreads();
  const float nrm = fmaxf(sqrtf(red[0] + red[1] + red[2] + red[3]), 1e-7f);
  out3[(size_t)bp * C3 + t] = v / nrm;
}

// ---------------- launch ----------------
extern "C" void kernel_launch(void* const* d_in, const int* in_sizes, int n_in,
                              void* d_out, int out_size, void* d_ws, size_t ws_size,
                              hipStream_t stream){
  const float* feat0 = (const float*)d_in[0];
  const float* feat1 = (const float*)d_in[1];
  const float* feat2 = (const float*)d_in[2];
  const float* feat3 = (const float*)d_in[3];
  const int*   pid0  = (const int*)d_in[4];
  const int*   pid1  = (const int*)d_in[5];
  const int*   pid2  = (const int*)d_in[6];

  float* out  = (float*)d_out;
  float* out0 = out;                 // 128*64
  float* out1 = out + 8192;          // 128*128
  float* out2 = out + 24576;         // 128*256
  float* out3 = out + 57344;         // 128*256

  float* ws       = (float*)d_ws;
  float* ent_ws   = ws;                         // 8192
  int*   idx_ws   = (int*)(ws + 8192);          // 128
  float* dotsl_ws = ws + 8320;                  // 2*49*4096 = 401408
  float* dg_ws    = dotsl_ws + 401408;          // 128*4096  = 524288
  float* bmax_ws  = dg_ws + 524288;             // 128*16
  float* oraw_ws  = bmax_ws + 2048;             // 128*256

  ldots_kernel<<<536, 1024, 0, stream>>>(feat3, dotsl_ws,
                                         feat0, feat1, feat2,
                                         pid0, pid1, pid2,
                                         out0, out1, out2);
  lent_kernel<<<128, 64, 0, stream>>>(dotsl_ws, ent_ws);
  rank_select_kernel<<<128, 256, 0, stream>>>(ent_ws, idx_ws);
  gdots_kernel<<<512, 256, 0, stream>>>(feat3, idx_ws, dg_ws, bmax_ws);
  pv_kernel<<<256, 256, 0, stream>>>(feat3, dg_ws, bmax_ws, oraw_ws);
  norm_kernel<<<128, 256, 0, stream>>>(oraw_ws, out3);
}